// Round 5
// baseline (482.690 us; speedup 1.0000x reference)
//
#include <hip/hip_runtime.h>
#include <hip/hip_bf16.h>
#include <stddef.h>
#include <stdint.h>

// ---------------------------------------------------------------------------
// bf16-MFMA transformer layer. B=2 T=2048 C=1024 H=16 HS=64 FF=4096, M=4096.
// Round 4: GEMM gets (1) 2-phase double-buffered prefetch (stage t+1 before
// compute t, one barrier per K-step), (2) bijective XCD blockIdx swizzle,
// (3) fused QKV (N=3072, OMODE3 epilogue: q|k normal + V transposed store).
// ---------------------------------------------------------------------------

constexpr int Bn = 2, Tn = 2048, Cn = 1024, Hn = 16, HSn = 64, FFn = 4096;
constexpr int Mn = Bn * Tn;
constexpr float EPSf = 1e-5f;
constexpr float S2 = 0.125f * 1.44269504088896340736f;  // HS^-0.5 * log2(e)

using short8 = __attribute__((ext_vector_type(8))) short;
using f32x4  = __attribute__((ext_vector_type(4))) float;
using s16x4  = __attribute__((ext_vector_type(4))) short;

#define DEVINL __device__ __forceinline__

DEVINL unsigned short f2bf(float f) {          // fp32 -> bf16 bits, RNE
  unsigned int u = __float_as_uint(f);
  u += 0x7fffu + ((u >> 16) & 1u);
  return (unsigned short)(u >> 16);
}

#define GLDS16(g, l) __builtin_amdgcn_global_load_lds(                        \
    (const __attribute__((address_space(1))) void*)(g),                       \
    (__attribute__((address_space(3))) void*)(l), 16, 0, 0)

// ---------------- transpose + fp32->bf16:  in [R][S] -> out [S][R] ---------
__global__ __launch_bounds__(256)
void transpose_cvt(const float* __restrict__ in, unsigned short* __restrict__ out,
                   int R, int S, long zin, long zout) {
  __shared__ float tile[32][33];
  const int c0 = blockIdx.x * 32;          // S dim
  const int r0 = blockIdx.y * 32;          // R dim
  in  += (size_t)blockIdx.z * zin;
  out += (size_t)blockIdx.z * zout;
  const int tid = threadIdx.x;
#pragma unroll
  for (int j = 0; j < 4; ++j) {
    const int f = tid + j * 256;
    tile[f >> 5][f & 31] = in[(size_t)(r0 + (f >> 5)) * S + c0 + (f & 31)];
  }
  __syncthreads();
#pragma unroll
  for (int j = 0; j < 4; ++j) {
    const int f = tid + j * 256;
    const int sr = f >> 5, rc = f & 31;
    out[(size_t)(c0 + sr) * R + r0 + rc] = f2bf(tile[rc][sr]);
  }
}

// ---------------- LayerNorm -> bf16 ----------------------------------------
__global__ __launch_bounds__(256)
void ln_bf16(const float* __restrict__ x, const float* __restrict__ w,
             unsigned short* __restrict__ out) {
  const int row = blockIdx.x, tid = threadIdx.x;
  const float4 v = ((const float4*)(x + (size_t)row * Cn))[tid];
  float s  = v.x + v.y + v.z + v.w;
  float ss = v.x*v.x + v.y*v.y + v.z*v.z + v.w*v.w;
#pragma unroll
  for (int o = 32; o > 0; o >>= 1) { s += __shfl_xor(s, o); ss += __shfl_xor(ss, o); }
  __shared__ float red[8];
  if ((tid & 63) == 0) { red[tid >> 6] = s; red[(tid >> 6) + 4] = ss; }
  __syncthreads();
  s  = red[0] + red[1] + red[2] + red[3];
  ss = red[4] + red[5] + red[6] + red[7];
  const float mu   = s * (1.0f / Cn);
  const float rstd = rsqrtf(ss * (1.0f / Cn) - mu * mu + EPSf);
  const float4 wv = ((const float4*)w)[tid];
  s16x4 o;
  o[0] = (short)f2bf((v.x - mu) * rstd * wv.x);
  o[1] = (short)f2bf((v.y - mu) * rstd * wv.y);
  o[2] = (short)f2bf((v.z - mu) * rstd * wv.z);
  o[3] = (short)f2bf((v.w - mu) * rstd * wv.w);
  ((s16x4*)(out + (size_t)row * Cn))[tid] = o;
}

// ---------------- bf16 MFMA GEMM: C[M,N] = A[M,K] * Bt[N,K]^T + bias --------
// 2-phase double-buffered: STAGE(next) issued before COMPUTE(cur); single
// __syncthreads per K-step drains vmcnt AFTER ~32 MFMAs covered the latency.
// EPI: 0 none, 1 relu, 2 +res(fp32).
// OMODE: 0 fp32 out, 1 bf16 out, 3 fused-QKV (n<2048 -> qk bf16 [M][2048];
//        n>=2048 -> vT[(m>>11)*1024 + n-2048][m&2047]).
template <int EPI, int OMODE>
__global__ __launch_bounds__(256)
void gemm_bf16(const unsigned short* __restrict__ A,
               const unsigned short* __restrict__ Bt,
               const float* __restrict__ bias, const float* __restrict__ res,
               void* __restrict__ outp, int M, int N, int K) {
  __shared__ unsigned short As[2][128][64];   // 32 KB, XOR-swizzled slots
  __shared__ unsigned short Bs[2][128][64];   // 32 KB
  const int tid = threadIdx.x;
  const int w = tid >> 6, l = tid & 63;
  const int wm = w >> 1, wn = w & 1;
  // bijective XCD swizzle (m204): consecutive swizzled ids -> same XCD chunk
  const int gx = gridDim.x, nwg = gx * gridDim.y;
  int wg = blockIdx.y * gx + blockIdx.x;
  {
    const int q = nwg >> 3, r = nwg & 7;
    const int xcd = wg & 7, off = wg >> 3;
    wg = (xcd < r ? xcd * (q + 1) : r * (q + 1) + (xcd - r) * q) + off;
  }
  const int m0 = (wg / gx) * 128, n0 = (wg % gx) * 128;

  f32x4 acc[4][4];
#pragma unroll
  for (int i = 0; i < 4; ++i)
#pragma unroll
    for (int j = 0; j < 4; ++j) acc[i][j] = (f32x4){0.f, 0.f, 0.f, 0.f};

  const unsigned short* Abase = A + (size_t)m0 * K;
  const unsigned short* Bbase = Bt + (size_t)n0 * K;

  // stage one 128x64 K-tile of A and B into buffer `as`/`bs`
  auto STAGE = [&](unsigned short* as, unsigned short* bs, int k0) {
#pragma unroll
    for (int j = 0; j < 4; ++j) {
      const int chunk = (w * 4 + j) * 64 + l;
      const int row = chunk >> 3, slot = chunk & 7;
      const size_t go = (size_t)row * K + k0 + ((slot ^ (row & 7)) << 3);
      GLDS16(Abase + go, as + (size_t)(w * 4 + j) * 512);
      GLDS16(Bbase + go, bs + (size_t)(w * 4 + j) * 512);
    }
  };
  auto COMPUTE = [&](const unsigned short (*as)[64], const unsigned short (*bs)[64]) {
#pragma unroll
    for (int kk = 0; kk < 2; ++kk) {
      short8 a[4], b[4];
#pragma unroll
      for (int i = 0; i < 4; ++i) {
        const int ar = wm * 64 + i * 16 + (l & 15);
        a[i] = *(const short8*)&as[ar][(((l >> 4) + kk * 4) ^ (ar & 7)) << 3];
        const int br = wn * 64 + i * 16 + (l & 15);
        b[i] = *(const short8*)&bs[br][(((l >> 4) + kk * 4) ^ (br & 7)) << 3];
      }
#pragma unroll
      for (int mi = 0; mi < 4; ++mi)
#pragma unroll
        for (int ni = 0; ni < 4; ++ni)
          acc[mi][ni] = __builtin_amdgcn_mfma_f32_16x16x32_bf16(
              a[mi], b[ni], acc[mi][ni], 0, 0, 0);
    }
  };

  const int nt = K >> 6;                     // even for K=1024/4096
  STAGE(&As[0][0][0], &Bs[0][0][0], 0);
  __syncthreads();
  for (int t = 0; t + 2 < nt; t += 2) {
    STAGE(&As[1][0][0], &Bs[1][0][0], (t + 1) << 6);
    COMPUTE(As[0], Bs[0]);
    __syncthreads();
    STAGE(&As[0][0][0], &Bs[0][0][0], (t + 2) << 6);
    COMPUTE(As[1], Bs[1]);
    __syncthreads();
  }
  STAGE(&As[1][0][0], &Bs[1][0][0], (nt - 1) << 6);
  COMPUTE(As[0], Bs[0]);
  __syncthreads();
  COMPUTE(As[1], Bs[1]);

  // ---- epilogue -----------------------------------------------------------
  if (OMODE == 3) {
    if (n0 < 2048) {                         // q|k region: bf16 [M][2048]
      unsigned short* qk = (unsigned short*)outp;
#pragma unroll
      for (int mi = 0; mi < 4; ++mi)
#pragma unroll
        for (int ni = 0; ni < 4; ++ni) {
          const int n = n0 + wn * 64 + ni * 16 + (l & 15);
          const float bv = bias[n];
#pragma unroll
          for (int r = 0; r < 4; ++r) {
            const int m = m0 + wm * 64 + mi * 16 + ((l >> 4) << 2) + r;
            qk[(size_t)m * 2048 + n] = f2bf(acc[mi][ni][r] + bv);
          }
        }
    } else {                                 // V region: transposed store
      unsigned short* vT = (unsigned short*)outp + (size_t)Mn * 2048;
#pragma unroll
      for (int mi = 0; mi < 4; ++mi)
#pragma unroll
        for (int ni = 0; ni < 4; ++ni) {
          const int n = n0 + wn * 64 + ni * 16 + (l & 15);
          const int nl = n - 2048;
          const int mbase = m0 + wm * 64 + mi * 16 + ((l >> 4) << 2);
          const int bb = mbase >> 11, t = mbase & 2047;
          const float bv = bias[n];
          unsigned short* dst = vT + ((size_t)(bb * 1024 + nl)) * Tn + t;
          unsigned int p0 = (unsigned)f2bf(acc[mi][ni][0] + bv) |
                            ((unsigned)f2bf(acc[mi][ni][1] + bv) << 16);
          unsigned int p1 = (unsigned)f2bf(acc[mi][ni][2] + bv) |
                            ((unsigned)f2bf(acc[mi][ni][3] + bv) << 16);
          *(unsigned int*)dst       = p0;
          *(unsigned int*)(dst + 2) = p1;
        }
    }
  } else {
#pragma unroll
    for (int mi = 0; mi < 4; ++mi)
#pragma unroll
      for (int ni = 0; ni < 4; ++ni) {
        const int n = n0 + wn * 64 + ni * 16 + (l & 15);
        const float bv = bias[n];
#pragma unroll
        for (int r = 0; r < 4; ++r) {
          const int m = m0 + wm * 64 + mi * 16 + ((l >> 4) << 2) + r;
          float v = acc[mi][ni][r] + bv;
          if (EPI == 1) v = fmaxf(v, 0.f);
          if (EPI == 2) v += res[(size_t)m * N + n];
          if (OMODE == 1) ((unsigned short*)outp)[(size_t)m * N + n] = f2bf(v);
          else            ((float*)outp)[(size_t)m * N + n] = v;
        }
      }
  }
}

// ---- stage one 64x64 bf16 tile (global row stride grs) into swizzled LDS --
DEVINL void stage64s(unsigned short* lds, const unsigned short* g, int grs,
                     int w, int l) {
#pragma unroll
  for (int j = 0; j < 2; ++j) {
    const int chunk = (w * 2 + j) * 64 + l;
    const int row = chunk >> 3, slot = chunk & 7;
    GLDS16(g + (size_t)row * grs + ((slot ^ (row & 7)) << 3),
           lds + (size_t)(w * 2 + j) * 512);
  }
}

// ---------------- Pass A: column softmax stats (exp2 domain) ----------------
__global__ __launch_bounds__(256)
void colstats_mfma(const unsigned short* __restrict__ qk,
                   float* __restrict__ m2buf, float* __restrict__ rlbuf) {
  __shared__ unsigned short Ks[64][64];
  __shared__ unsigned short Qs[64][64];
  __shared__ float redm[4][4][16], redl[4][4][16];
  const int j0 = blockIdx.x * 64;
  const int bh = blockIdx.y, b = bh >> 4, h = bh & 15;
  const int tid = threadIdx.x, w = tid >> 6, l = tid & 63;
  const unsigned short* kbase = qk + ((size_t)(b * Tn + j0)) * 2048 + 1024 + h * 64;
  const unsigned short* qbase = qk + ((size_t)(b * Tn)) * 2048 + h * 64;
  stage64s(&Ks[0][0], kbase, 2048, w, l);
  float m2[4], ls[4];
#pragma unroll
  for (int ni = 0; ni < 4; ++ni) { m2[ni] = -1e30f; ls[ni] = 0.f; }

  for (int i0 = j0; i0 < Tn; i0 += 64) {
    __syncthreads();
    stage64s(&Qs[0][0], qbase + (size_t)i0 * 2048, 2048, w, l);
    __syncthreads();
    f32x4 s[4];
#pragma unroll
    for (int ni = 0; ni < 4; ++ni) s[ni] = (f32x4){0.f, 0.f, 0.f, 0.f};
#pragma unroll
    for (int kk = 0; kk < 2; ++kk) {
      const int ar = w * 16 + (l & 15);
      const short8 af = *(const short8*)&Qs[ar][(((l >> 4) + kk * 4) ^ (ar & 7)) << 3];
#pragma unroll
      for (int ni = 0; ni < 4; ++ni) {
        const int br = ni * 16 + (l & 15);
        const short8 bfr = *(const short8*)&Ks[br][(((l >> 4) + kk * 4) ^ (br & 7)) << 3];
        s[ni] = __builtin_amdgcn_mfma_f32_16x16x32_bf16(af, bfr, s[ni], 0, 0, 0);
      }
    }
    const bool diag = (i0 == j0);
    const int ib = w * 16 + ((l >> 4) << 2);
#pragma unroll
    for (int ni = 0; ni < 4; ++ni) {
      const int jl = ni * 16 + (l & 15);
      float v0 = s[ni][0] * S2, v1 = s[ni][1] * S2, v2 = s[ni][2] * S2, v3 = s[ni][3] * S2;
      if (!diag) {
        const float tmax = fmaxf(fmaxf(v0, v1), fmaxf(v2, v3));
        const float mn = fmaxf(m2[ni], tmax);
        ls[ni] = ls[ni] * exp2f(m2[ni] - mn) +
                 exp2f(v0 - mn) + exp2f(v1 - mn) + exp2f(v2 - mn) + exp2f(v3 - mn);
        m2[ni] = mn;
      } else {
        const bool g0 = (ib + 0 >= jl), g1 = (ib + 1 >= jl), g2 = (ib + 2 >= jl), g3 = (ib + 3 >= jl);
        const float t0 = g0 ? v0 : -1e30f, t1 = g1 ? v1 : -1e30f;
        const float t2 = g2 ? v2 : -1e30f, t3 = g3 ? v3 : -1e30f;
        const float tmax = fmaxf(fmaxf(t0, t1), fmaxf(t2, t3));
        const float mn = fmaxf(m2[ni], tmax);
        const float e0 = g0 ? exp2f(v0 - mn) : 0.f;
        const float e1 = g1 ? exp2f(v1 - mn) : 0.f;
        const float e2 = g2 ? exp2f(v2 - mn) : 0.f;
        const float e3 = g3 ? exp2f(v3 - mn) : 0.f;
        ls[ni] = ls[ni] * exp2f(m2[ni] - mn) + e0 + e1 + e2 + e3;
        m2[ni] = mn;
      }
    }
  }
  // combine across lane groups (same column j, different row subsets)
#pragma unroll
  for (int ni = 0; ni < 4; ++ni) {
#pragma unroll
    for (int off = 16; off < 64; off <<= 1) {
      const float mo = __shfl_xor(m2[ni], off);
      const float lo = __shfl_xor(ls[ni], off);
      const float mn = fmaxf(m2[ni], mo);
      ls[ni] = ls[ni] * exp2f(m2[ni] - mn) + lo * exp2f(mo - mn);
      m2[ni] = mn;
    }
  }
  if (l < 16) {
#pragma unroll
    for (int ni = 0; ni < 4; ++ni) { redm[w][ni][l] = m2[ni]; redl[w][ni][l] = ls[ni]; }
  }
  __syncthreads();
  if (tid < 64) {
    const int ni = tid >> 4, jl = tid & 15;
    float m = redm[0][ni][jl], sl = redl[0][ni][jl];
#pragma unroll
    for (int wv = 1; wv < 4; ++wv) {
      const float mo = redm[wv][ni][jl], lo = redl[wv][ni][jl];
      const float mn = fmaxf(m, mo);
      sl = sl * exp2f(m - mn) + lo * exp2f(mo - mn);
      m = mn;
    }
    m2buf[(size_t)bh * Tn + j0 + ni * 16 + jl] = m;
    rlbuf[(size_t)bh * Tn + j0 + ni * 16 + jl] = 1.0f / sl;
  }
}

// ---------------- Pass B: att = P * V  (P wave-private via swizzled LDS) ----
__global__ __launch_bounds__(256)
void pv_mfma(const unsigned short* __restrict__ qk,
             const unsigned short* __restrict__ vT,
             const float* __restrict__ m2buf, const float* __restrict__ rlbuf,
             unsigned short* __restrict__ att) {
  __shared__ unsigned short Qs[64][64];
  __shared__ unsigned short Ks[64][64];
  __shared__ unsigned short Vs[64][64];   // [d][j]
  __shared__ unsigned short Ps[64][64];   // [i][j], XOR-swizzled
  __shared__ float m2s[64], rls[64];
  const int i0 = blockIdx.x * 64;
  const int bh = blockIdx.y, b = bh >> 4, h = bh & 15;
  const int tid = threadIdx.x, w = tid >> 6, l = tid & 63;
  const unsigned short* qbase = qk + ((size_t)(b * Tn + i0)) * 2048 + h * 64;
  const unsigned short* kbase = qk + ((size_t)(b * Tn)) * 2048 + 1024 + h * 64;
  const unsigned short* vbase = vT + ((size_t)(b * 1024 + h * 64)) * Tn;
  stage64s(&Qs[0][0], qbase, 2048, w, l);
  f32x4 oacc[4];
#pragma unroll
  for (int ni = 0; ni < 4; ++ni) oacc[ni] = (f32x4){0.f, 0.f, 0.f, 0.f};

  for (int j0 = 0; j0 <= i0; j0 += 64) {
    __syncthreads();
    stage64s(&Ks[0][0], kbase + (size_t)j0 * 2048, 2048, w, l);
#pragma unroll
    for (int j = 0; j < 2; ++j) {          // V tile [d][j], rows are vT rows
      const int chunk = (w * 2 + j) * 64 + l;
      const int row = chunk >> 3, slot = chunk & 7;
      GLDS16(vbase + (size_t)row * Tn + j0 + ((slot ^ (row & 7)) << 3),
             &Vs[0][0] + (size_t)(w * 2 + j) * 512);
    }
    if (tid < 64) {
      m2s[tid] = m2buf[(size_t)bh * Tn + j0 + tid];
      rls[tid] = rlbuf[(size_t)bh * Tn + j0 + tid];
    }
    __syncthreads();
    // S = Q K^T (this wave's 16 rows x 64 cols)
    f32x4 s[4];
#pragma unroll
    for (int ni = 0; ni < 4; ++ni) s[ni] = (f32x4){0.f, 0.f, 0.f, 0.f};
#pragma unroll
    for (int kk = 0; kk < 2; ++kk) {
      const int ar = w * 16 + (l & 15);
      const short8 af = *(const short8*)&Qs[ar][(((l >> 4) + kk * 4) ^ (ar & 7)) << 3];
#pragma unroll
      for (int ni = 0; ni < 4; ++ni) {
        const int br = ni * 16 + (l & 15);
        const short8 bfr = *(const short8*)&Ks[br][(((l >> 4) + kk * 4) ^ (br & 7)) << 3];
        s[ni] = __builtin_amdgcn_mfma_f32_16x16x32_bf16(af, bfr, s[ni], 0, 0, 0);
      }
    }
    // P = exp2(s2 - m2_j) * rl_j  (masked), write to wave-private Ps rows
    const bool diag = (j0 == i0);
    const int ib = w * 16 + ((l >> 4) << 2);
    unsigned short* Pf = &Ps[0][0];
#pragma unroll
    for (int ni = 0; ni < 4; ++ni) {
      const int jl = ni * 16 + (l & 15);
      const float mj = m2s[jl], rj = rls[jl];
#pragma unroll
      for (int r = 0; r < 4; ++r) {
        float p = exp2f(s[ni][r] * S2 - mj) * rj;
        if (diag && (ib + r < jl)) p = 0.f;
        const int il = ib + r;
        Pf[il * 64 + (((jl >> 3) ^ (il & 7)) << 3) + (jl & 7)] = f2bf(p);
      }
    }
    // O += P V   (A = Ps rows i [wave-private], B = Vs rows d)
#pragma unroll
    for (int kk = 0; kk < 2; ++kk) {
      const int ar = w * 16 + (l & 15);
      const short8 pf = *(const short8*)&Ps[ar][(((l >> 4) + kk * 4) ^ (ar & 7)) << 3];
#pragma unroll
      for (int ni = 0; ni < 4; ++ni) {
        const int br = ni * 16 + (l & 15);
        const short8 vf = *(const short8*)&Vs[br][(((l >> 4) + kk * 4) ^ (br & 7)) << 3];
        oacc[ni] = __builtin_amdgcn_mfma_f32_16x16x32_bf16(pf, vf, oacc[ni], 0, 0, 0);
      }
    }
  }
#pragma unroll
  for (int ni = 0; ni < 4; ++ni) {
    const int col = h * 64 + ni * 16 + (l & 15);
#pragma unroll
    for (int r = 0; r < 4; ++r) {
      const int m = b * Tn + i0 + w * 16 + ((l >> 4) << 2) + r;
      att[(size_t)m * 1024 + col] = f2bf(oacc[ni][r]);
    }
  }
}

// ---------------------------------------------------------------------------
extern "C" void kernel_launch(void* const* d_in, const int* in_sizes, int n_in,
                              void* d_out, int out_size, void* d_ws, size_t ws_size,
                              hipStream_t stream) {
  const float* x    = (const float*)d_in[0];
  const float* ln1w = (const float*)d_in[1];
  const float* Wq   = (const float*)d_in[2];
  const float* bq   = (const float*)d_in[3];
  const float* Wk   = (const float*)d_in[4];
  const float* bk   = (const float*)d_in[5];
  const float* Wv   = (const float*)d_in[6];
  const float* bv   = (const float*)d_in[7];
  const float* Wo   = (const float*)d_in[8];
  const float* bo   = (const float*)d_in[9];
  const float* ln2w = (const float*)d_in[10];
  const float* W1   = (const float*)d_in[11];
  const float* b1   = (const float*)d_in[12];
  const float* W2   = (const float*)d_in[13];
  const float* b2   = (const float*)d_in[14];

  uint8_t* wsb = (uint8_t*)d_ws;
  unsigned short* h     = (unsigned short*)(wsb);                    // 8 MB
  unsigned short* qkb   = (unsigned short*)(wsb + (8ull  << 20));    // 16 MB (q|k)
  unsigned short* vT    = (unsigned short*)(wsb + (24ull << 20));    // 8 MB (=qkb+Mn*2048)
  unsigned short* attb  = (unsigned short*)(wsb + (32ull << 20));    // 8 MB
  float*          x1    = (float*)         (wsb + (40ull << 20));    // 16 MB
  unsigned short* ffmid = qkb;   // reuses qkb+vT+attb (32 MB), dead by then
  unsigned short* Wqkvt = (unsigned short*)(wsb + (56ull << 20));    // 6 MB [3072][1024]
  unsigned short* Wot   = (unsigned short*)(wsb + (62ull << 20));    // 2 MB
  unsigned short* W1t   = (unsigned short*)(wsb + (64ull << 20));    // 8 MB
  unsigned short* W2t   = (unsigned short*)(wsb + (72ull << 20));    // 8 MB
  float*          biasqkv=(float*)         (wsb + (80ull << 20));    // 12 KB
  float*          m2buf = (float*)         (wsb + (81ull << 20));    // 256 KB
  float*          rlbuf = (float*)         (wsb + (81ull << 20) + (256ull << 10));

  // weights -> bf16 B^T.  Wqkvt rows: [0,2048)=Wq|Wk, [2048,3072)=Wv.
  transpose_cvt<<<dim3(2, 32, 16), 256, 0, stream>>>(Wq, Wqkvt,                  1024, 64, 65536, 65536);
  transpose_cvt<<<dim3(2, 32, 16), 256, 0, stream>>>(Wk, Wqkvt + 1024 * 1024,    1024, 64, 65536, 65536);
  transpose_cvt<<<dim3(2, 32, 16), 256, 0, stream>>>(Wv, Wqkvt + 2 * 1024 * 1024, 1024, 64, 65536, 65536);
  transpose_cvt<<<dim3(32, 32, 1), 256, 0, stream>>>(Wo, Wot,  1024, 1024, 0, 0);
  transpose_cvt<<<dim3(128, 32, 1), 256, 0, stream>>>(W1, W1t, 1024, 4096, 0, 0);
  transpose_cvt<<<dim3(32, 128, 1), 256, 0, stream>>>(W2, W2t, 4096, 1024, 0, 0);
  hipMemcpyAsync(biasqkv,        bq, 1024 * sizeof(float), hipMemcpyDeviceToDevice, stream);
  hipMemcpyAsync(biasqkv + 1024, bk, 1024 * sizeof(float), hipMemcpyDeviceToDevice, stream);
  hipMemcpyAsync(biasqkv + 2048, bv, 1024 * sizeof(float), hipMemcpyDeviceToDevice, stream);

  // 1. LN1 -> h (bf16)
  ln_bf16<<<Mn, 256, 0, stream>>>(x, ln1w, h);
  // 2. fused q|k|v = h @ Wqkv  (N=3072; q|k -> qkb, v -> vT transposed)
  gemm_bf16<0, 3><<<dim3(24, 32), 256, 0, stream>>>(h, Wqkvt, biasqkv, nullptr, qkb, Mn, 3072, Cn);
  // 3/4. column-softmax attention
  colstats_mfma<<<dim3(Tn / 64, Bn * Hn), 256, 0, stream>>>(qkb, m2buf, rlbuf);
  pv_mfma<<<dim3(Tn / 64, Bn * Hn), 256, 0, stream>>>(qkb, vT, m2buf, rlbuf, attb);
  // 5. x1 = att @ Wo + bo + x  (fp32 out)
  gemm_bf16<2, 0><<<dim3(8, 32), 256, 0, stream>>>(attb, Wot, bo, x, x1, Mn, 1024, Cn);
  // 6. LN2 -> h (bf16)
  ln_bf16<<<Mn, 256, 0, stream>>>(x1, ln2w, h);
  // 7. ffmid = relu(h @ W1 + b1)  (bf16 out)
  gemm_bf16<1, 1><<<dim3(32, 32), 256, 0, stream>>>(h, W1t, b1, nullptr, ffmid, Mn, FFn, Cn);
  // 8. out = ffmid @ W2 + b2 + x1 (fp32 out)
  gemm_bf16<2, 0><<<dim3(8, 32), 256, 0, stream>>>(ffmid, W2t, b2, x1, (float*)d_out, Mn, Cn, FFn);
}

// Round 7
// 423.005 us; speedup vs baseline: 1.1411x; 1.1411x over previous
//
#include <hip/hip_runtime.h>
#include <hip/hip_bf16.h>
#include <stddef.h>
#include <stdint.h>

// ---------------------------------------------------------------------------
// bf16-MFMA transformer layer. B=2 T=2048 C=1024 H=16 HS=64 FF=4096, M=4096.
// Round 7 (= round 6 + race fix): (1) triangle-paired attention blocks,
// with a barrier before each half's Q re-stage (fixes cross-half LDS race),
// (2) per-GEMM pipeline choice: single-buffer (occupancy) vs dbuf (ILP),
// (3) FFN2 split-K=2 with fp32 atomic accumulation after init_out.
// ---------------------------------------------------------------------------

constexpr int Bn = 2, Tn = 2048, Cn = 1024, Hn = 16, HSn = 64, FFn = 4096;
constexpr int Mn = Bn * Tn;
constexpr float EPSf = 1e-5f;
constexpr float S2 = 0.125f * 1.44269504088896340736f;  // HS^-0.5 * log2(e)

using short8 = __attribute__((ext_vector_type(8))) short;
using f32x4  = __attribute__((ext_vector_type(4))) float;
using s16x4  = __attribute__((ext_vector_type(4))) short;

#define DEVINL __device__ __forceinline__

DEVINL unsigned short f2bf(float f) {          // fp32 -> bf16 bits, RNE
  unsigned int u = __float_as_uint(f);
  u += 0x7fffu + ((u >> 16) & 1u);
  return (unsigned short)(u >> 16);
}

#define GLDS16(g, l) __builtin_amdgcn_global_load_lds(                        \
    (const __attribute__((address_space(1))) void*)(g),                       \
    (__attribute__((address_space(3))) void*)(l), 16, 0, 0)

// ---------------- transpose + fp32->bf16:  in [R][S] -> out [S][R] ---------
__global__ __launch_bounds__(256)
void transpose_cvt(const float* __restrict__ in, unsigned short* __restrict__ out,
                   int R, int S, long zin, long zout) {
  __shared__ float tile[32][33];
  const int c0 = blockIdx.x * 32;          // S dim
  const int r0 = blockIdx.y * 32;          // R dim
  in  += (size_t)blockIdx.z * zin;
  out += (size_t)blockIdx.z * zout;
  const int tid = threadIdx.x;
#pragma unroll
  for (int j = 0; j < 4; ++j) {
    const int f = tid + j * 256;
    tile[f >> 5][f & 31] = in[(size_t)(r0 + (f >> 5)) * S + c0 + (f & 31)];
  }
  __syncthreads();
#pragma unroll
  for (int j = 0; j < 4; ++j) {
    const int f = tid + j * 256;
    const int sr = f >> 5, rc = f & 31;
    out[(size_t)(c0 + sr) * R + r0 + rc] = f2bf(tile[rc][sr]);
  }
}

// ---------------- LayerNorm -> bf16 ----------------------------------------
__global__ __launch_bounds__(256)
void ln_bf16(const float* __restrict__ x, const float* __restrict__ w,
             unsigned short* __restrict__ out) {
  const int row = blockIdx.x, tid = threadIdx.x;
  const float4 v = ((const float4*)(x + (size_t)row * Cn))[tid];
  float s  = v.x + v.y + v.z + v.w;
  float ss = v.x*v.x + v.y*v.y + v.z*v.z + v.w*v.w;
#pragma unroll
  for (int o = 32; o > 0; o >>= 1) { s += __shfl_xor(s, o); ss += __shfl_xor(ss, o); }
  __shared__ float red[8];
  if ((tid & 63) == 0) { red[tid >> 6] = s; red[(tid >> 6) + 4] = ss; }
  __syncthreads();
  s  = red[0] + red[1] + red[2] + red[3];
  ss = red[4] + red[5] + red[6] + red[7];
  const float mu   = s * (1.0f / Cn);
  const float rstd = rsqrtf(ss * (1.0f / Cn) - mu * mu + EPSf);
  const float4 wv = ((const float4*)w)[tid];
  s16x4 o;
  o[0] = (short)f2bf((v.x - mu) * rstd * wv.x);
  o[1] = (short)f2bf((v.y - mu) * rstd * wv.y);
  o[2] = (short)f2bf((v.z - mu) * rstd * wv.z);
  o[3] = (short)f2bf((v.w - mu) * rstd * wv.w);
  ((s16x4*)(out + (size_t)row * Cn))[tid] = o;
}

// ---------------- out = b2 (broadcast over rows) + x1 ----------------------
__global__ __launch_bounds__(256)
void init_out(const float* __restrict__ b2, const float* __restrict__ x1,
              float* __restrict__ out) {
  const int idx = blockIdx.x * 256 + threadIdx.x;      // float4 index
  const float4 xv = ((const float4*)x1)[idx];
  const float4 bb = ((const float4*)b2)[idx & 255];    // Cn/4 = 256 per row
  float4 o;
  o.x = xv.x + bb.x; o.y = xv.y + bb.y; o.z = xv.z + bb.z; o.w = xv.w + bb.w;
  ((float4*)out)[idx] = o;
}

// ---------------- bf16 MFMA GEMM: C[M,N] = A[M,K] * Bt[N,K]^T + bias --------
// PIPE 0: single-buffer (32 KB LDS, max blocks/CU — for large grids).
// PIPE 1: double-buffered prefetch (64 KB — for grid-starved 1-2 blk/CU).
// Split-K via gridDim.z (chunk kpb = K/gz); use EPI=3 then.
// EPI: 0 +bias, 1 +bias relu, 2 +bias +res(fp32), 3 atomicAdd (no bias).
// OMODE: 0 fp32 out, 1 bf16 out, 3 fused-QKV (n<2048 -> qk bf16 [M][2048];
//        n>=2048 -> vT[(m>>11)*1024 + n-2048][m&2047]).
template <int EPI, int OMODE, int PIPE>
__global__ __launch_bounds__(256)
void gemm_bf16(const unsigned short* __restrict__ A,
               const unsigned short* __restrict__ Bt,
               const float* __restrict__ bias, const float* __restrict__ res,
               void* __restrict__ outp, int M, int N, int K) {
  __shared__ unsigned short As[PIPE + 1][128][64];   // XOR-swizzled slots
  __shared__ unsigned short Bs[PIPE + 1][128][64];
  const int tid = threadIdx.x;
  const int w = tid >> 6, l = tid & 63;
  const int wm = w >> 1, wn = w & 1;
  // bijective XCD swizzle (m204); z-chunks share the same (m,n)->XCD map
  const int gx = gridDim.x, nwg = gx * gridDim.y;
  int wg = blockIdx.y * gx + blockIdx.x;
  {
    const int q = nwg >> 3, r = nwg & 7;
    const int xcd = wg & 7, off = wg >> 3;
    wg = (xcd < r ? xcd * (q + 1) : r * (q + 1) + (xcd - r) * q) + off;
  }
  const int m0 = (wg / gx) * 128, n0 = (wg % gx) * 128;
  const int kpb = K / gridDim.z;                  // split-K chunk size
  const int kbase = blockIdx.z * kpb;

  f32x4 acc[4][4];
#pragma unroll
  for (int i = 0; i < 4; ++i)
#pragma unroll
    for (int j = 0; j < 4; ++j) acc[i][j] = (f32x4){0.f, 0.f, 0.f, 0.f};

  const unsigned short* Abase = A + (size_t)m0 * K + kbase;
  const unsigned short* Bbase = Bt + (size_t)n0 * K + kbase;

  auto STAGE = [&](unsigned short* as, unsigned short* bs, int k0) {
#pragma unroll
    for (int j = 0; j < 4; ++j) {
      const int chunk = (w * 4 + j) * 64 + l;
      const int row = chunk >> 3, slot = chunk & 7;
      const size_t go = (size_t)row * K + k0 + ((slot ^ (row & 7)) << 3);
      GLDS16(Abase + go, as + (size_t)(w * 4 + j) * 512);
      GLDS16(Bbase + go, bs + (size_t)(w * 4 + j) * 512);
    }
  };
  auto COMPUTE = [&](const unsigned short (*as)[64], const unsigned short (*bs)[64]) {
#pragma unroll
    for (int kk = 0; kk < 2; ++kk) {
      short8 a[4], b[4];
#pragma unroll
      for (int i = 0; i < 4; ++i) {
        const int ar = wm * 64 + i * 16 + (l & 15);
        a[i] = *(const short8*)&as[ar][(((l >> 4) + kk * 4) ^ (ar & 7)) << 3];
        const int br = wn * 64 + i * 16 + (l & 15);
        b[i] = *(const short8*)&bs[br][(((l >> 4) + kk * 4) ^ (br & 7)) << 3];
      }
#pragma unroll
      for (int mi = 0; mi < 4; ++mi)
#pragma unroll
        for (int ni = 0; ni < 4; ++ni)
          acc[mi][ni] = __builtin_amdgcn_mfma_f32_16x16x32_bf16(
              a[mi], b[ni], acc[mi][ni], 0, 0, 0);
    }
  };

  const int nt = kpb >> 6;
  if (PIPE == 1) {                                // dbuf prefetch (nt even)
    STAGE(&As[0][0][0], &Bs[0][0][0], 0);
    __syncthreads();
    for (int t = 0; t + 2 < nt; t += 2) {
      STAGE(&As[1][0][0], &Bs[1][0][0], (t + 1) << 6);
      COMPUTE(As[0], Bs[0]);
      __syncthreads();
      STAGE(&As[0][0][0], &Bs[0][0][0], (t + 2) << 6);
      COMPUTE(As[1], Bs[1]);
      __syncthreads();
    }
    STAGE(&As[1][0][0], &Bs[1][0][0], (nt - 1) << 6);
    COMPUTE(As[0], Bs[0]);
    __syncthreads();
    COMPUTE(As[1], Bs[1]);
  } else {                                        // single-buffer (m97 style)
    for (int t = 0; t < nt; ++t) {
      if (t) __syncthreads();
      STAGE(&As[0][0][0], &Bs[0][0][0], t << 6);
      __syncthreads();
      COMPUTE(As[0], Bs[0]);
    }
  }

  // ---- epilogue -----------------------------------------------------------
  if (OMODE == 3) {
    if (n0 < 2048) {                         // q|k region: bf16 [M][2048]
      unsigned short* qk = (unsigned short*)outp;
#pragma unroll
      for (int mi = 0; mi < 4; ++mi)
#pragma unroll
        for (int ni = 0; ni < 4; ++ni) {
          const int n = n0 + wn * 64 + ni * 16 + (l & 15);
          const float bv = bias[n];
#pragma unroll
          for (int r = 0; r < 4; ++r) {
            const int m = m0 + wm * 64 + mi * 16 + ((l >> 4) << 2) + r;
            qk[(size_t)m * 2048 + n] = f2bf(acc[mi][ni][r] + bv);
          }
        }
    } else {                                 // V region: transposed store
      unsigned short* vT = (unsigned short*)outp + (size_t)Mn * 2048;
#pragma unroll
      for (int mi = 0; mi < 4; ++mi)
#pragma unroll
        for (int ni = 0; ni < 4; ++ni) {
          const int n = n0 + wn * 64 + ni * 16 + (l & 15);
          const int nl = n - 2048;
          const int mbase = m0 + wm * 64 + mi * 16 + ((l >> 4) << 2);
          const int bb = mbase >> 11, t = mbase & 2047;
          const float bv = bias[n];
          unsigned short* dst = vT + ((size_t)(bb * 1024 + nl)) * Tn + t;
          unsigned int p0 = (unsigned)f2bf(acc[mi][ni][0] + bv) |
                            ((unsigned)f2bf(acc[mi][ni][1] + bv) << 16);
          unsigned int p1 = (unsigned)f2bf(acc[mi][ni][2] + bv) |
                            ((unsigned)f2bf(acc[mi][ni][3] + bv) << 16);
          *(unsigned int*)dst       = p0;
          *(unsigned int*)(dst + 2) = p1;
        }
    }
  } else {
#pragma unroll
    for (int mi = 0; mi < 4; ++mi)
#pragma unroll
      for (int ni = 0; ni < 4; ++ni) {
        const int n = n0 + wn * 64 + ni * 16 + (l & 15);
        const float bv = (EPI == 3) ? 0.f : bias[n];
#pragma unroll
        for (int r = 0; r < 4; ++r) {
          const int m = m0 + wm * 64 + mi * 16 + ((l >> 4) << 2) + r;
          if (EPI == 3) {
            unsafeAtomicAdd(&((float*)outp)[(size_t)m * N + n], acc[mi][ni][r]);
          } else {
            float v = acc[mi][ni][r] + bv;
            if (EPI == 1) v = fmaxf(v, 0.f);
            if (EPI == 2) v += res[(size_t)m * N + n];
            if (OMODE == 1) ((unsigned short*)outp)[(size_t)m * N + n] = f2bf(v);
            else            ((float*)outp)[(size_t)m * N + n] = v;
          }
        }
      }
  }
}

// ---- stage one 64x64 bf16 tile (global row stride grs) into swizzled LDS --
DEVINL void stage64s(unsigned short* lds, const unsigned short* g, int grs,
                     int w, int l) {
#pragma unroll
  for (int j = 0; j < 2; ++j) {
    const int chunk = (w * 2 + j) * 64 + l;
    const int row = chunk >> 3, slot = chunk & 7;
    GLDS16(g + (size_t)row * grs + ((slot ^ (row & 7)) << 3),
           lds + (size_t)(w * 2 + j) * 512);
  }
}

// ---------------- Pass A: column softmax stats (exp2 domain) ----------------
// Triangle-paired: block bx handles column tiles {bx, 31-bx} -> 33 tiles each.
__global__ __launch_bounds__(256)
void colstats_mfma(const unsigned short* __restrict__ qk,
                   float* __restrict__ m2buf, float* __restrict__ rlbuf) {
  __shared__ unsigned short Ks[64][64];
  __shared__ unsigned short Qs[64][64];
  __shared__ float redm[4][4][16], redl[4][4][16];
  const int bx = blockIdx.x;
  const int bh = blockIdx.y, b = bh >> 4, h = bh & 15;
  const int tid = threadIdx.x, w = tid >> 6, l = tid & 63;
  const unsigned short* qbase = qk + ((size_t)(b * Tn)) * 2048 + h * 64;

  for (int half = 0; half < 2; ++half) {
    const int jt = half ? (31 - bx) : bx;
    const int j0 = jt * 64;
    const unsigned short* kbase = qk + ((size_t)(b * Tn + j0)) * 2048 + 1024 + h * 64;
    stage64s(&Ks[0][0], kbase, 2048, w, l);
    float m2[4], ls[4];
#pragma unroll
    for (int ni = 0; ni < 4; ++ni) { m2[ni] = -1e30f; ls[ni] = 0.f; }

    for (int i0 = j0; i0 < Tn; i0 += 64) {
      __syncthreads();
      stage64s(&Qs[0][0], qbase + (size_t)i0 * 2048, 2048, w, l);
      __syncthreads();
      f32x4 s[4];
#pragma unroll
      for (int ni = 0; ni < 4; ++ni) s[ni] = (f32x4){0.f, 0.f, 0.f, 0.f};
#pragma unroll
      for (int kk = 0; kk < 2; ++kk) {
        const int ar = w * 16 + (l & 15);
        const short8 af = *(const short8*)&Qs[ar][(((l >> 4) + kk * 4) ^ (ar & 7)) << 3];
#pragma unroll
        for (int ni = 0; ni < 4; ++ni) {
          const int br = ni * 16 + (l & 15);
          const short8 bfr = *(const short8*)&Ks[br][(((l >> 4) + kk * 4) ^ (br & 7)) << 3];
          s[ni] = __builtin_amdgcn_mfma_f32_16x16x32_bf16(af, bfr, s[ni], 0, 0, 0);
        }
      }
      const bool diag = (i0 == j0);
      const int ib = w * 16 + ((l >> 4) << 2);
#pragma unroll
      for (int ni = 0; ni < 4; ++ni) {
        const int jl = ni * 16 + (l & 15);
        float v0 = s[ni][0] * S2, v1 = s[ni][1] * S2, v2 = s[ni][2] * S2, v3 = s[ni][3] * S2;
        if (!diag) {
          const float tmax = fmaxf(fmaxf(v0, v1), fmaxf(v2, v3));
          const float mn = fmaxf(m2[ni], tmax);
          ls[ni] = ls[ni] * exp2f(m2[ni] - mn) +
                   exp2f(v0 - mn) + exp2f(v1 - mn) + exp2f(v2 - mn) + exp2f(v3 - mn);
          m2[ni] = mn;
        } else {
          const bool g0 = (ib + 0 >= jl), g1 = (ib + 1 >= jl), g2 = (ib + 2 >= jl), g3 = (ib + 3 >= jl);
          const float t0 = g0 ? v0 : -1e30f, t1 = g1 ? v1 : -1e30f;
          const float t2 = g2 ? v2 : -1e30f, t3 = g3 ? v3 : -1e30f;
          const float tmax = fmaxf(fmaxf(t0, t1), fmaxf(t2, t3));
          const float mn = fmaxf(m2[ni], tmax);
          const float e0 = g0 ? exp2f(v0 - mn) : 0.f;
          const float e1 = g1 ? exp2f(v1 - mn) : 0.f;
          const float e2 = g2 ? exp2f(v2 - mn) : 0.f;
          const float e3 = g3 ? exp2f(v3 - mn) : 0.f;
          ls[ni] = ls[ni] * exp2f(m2[ni] - mn) + e0 + e1 + e2 + e3;
          m2[ni] = mn;
        }
      }
    }
    // combine across lane groups (same column j, different row subsets)
#pragma unroll
    for (int ni = 0; ni < 4; ++ni) {
#pragma unroll
      for (int off = 16; off < 64; off <<= 1) {
        const float mo = __shfl_xor(m2[ni], off);
        const float lo = __shfl_xor(ls[ni], off);
        const float mn = fmaxf(m2[ni], mo);
        ls[ni] = ls[ni] * exp2f(m2[ni] - mn) + lo * exp2f(mo - mn);
        m2[ni] = mn;
      }
    }
    if (l < 16) {
#pragma unroll
      for (int ni = 0; ni < 4; ++ni) { redm[w][ni][l] = m2[ni]; redl[w][ni][l] = ls[ni]; }
    }
    __syncthreads();
    if (tid < 64) {
      const int ni = tid >> 4, jl = tid & 15;
      float m = redm[0][ni][jl], sl = redl[0][ni][jl];
#pragma unroll
      for (int wv = 1; wv < 4; ++wv) {
        const float mo = redm[wv][ni][jl], lo = redl[wv][ni][jl];
        const float mn = fmaxf(m, mo);
        sl = sl * exp2f(m - mn) + lo * exp2f(mo - mn);
        m = mn;
      }
      m2buf[(size_t)bh * Tn + j0 + ni * 16 + jl] = m;
      rlbuf[(size_t)bh * Tn + j0 + ni * 16 + jl] = 1.0f / sl;
    }
    __syncthreads();   // redm/redl reads done before next half rewrites
  }
}

// ---------------- Pass B: att = P * V  (triangle-paired row tiles) ----------
__global__ __launch_bounds__(256)
void pv_mfma(const unsigned short* __restrict__ qk,
             const unsigned short* __restrict__ vT,
             const float* __restrict__ m2buf, const float* __restrict__ rlbuf,
             unsigned short* __restrict__ att) {
  __shared__ unsigned short Qs[64][64];
  __shared__ unsigned short Ks[64][64];
  __shared__ unsigned short Vs[64][64];   // [d][j]
  __shared__ unsigned short Ps[64][64];   // [i][j], XOR-swizzled
  __shared__ float m2s[64], rls[64];
  const int bx = blockIdx.x;
  const int bh = blockIdx.y, b = bh >> 4, h = bh & 15;
  const int tid = threadIdx.x, w = tid >> 6, l = tid & 63;
  const unsigned short* kbase = qk + ((size_t)(b * Tn)) * 2048 + 1024 + h * 64;
  const unsigned short* vbase = vT + ((size_t)(b * 1024 + h * 64)) * Tn;

  for (int half = 0; half < 2; ++half) {
    const int it = half ? (31 - bx) : bx;
    const int i0 = it * 64;
    const unsigned short* qbase = qk + ((size_t)(b * Tn + i0)) * 2048 + h * 64;
    // RACE FIX: all waves must finish reading Qs (prev half) before re-stage.
    __syncthreads();
    stage64s(&Qs[0][0], qbase, 2048, w, l);
    f32x4 oacc[4];
#pragma unroll
    for (int ni = 0; ni < 4; ++ni) oacc[ni] = (f32x4){0.f, 0.f, 0.f, 0.f};

    for (int j0 = 0; j0 <= i0; j0 += 64) {
      __syncthreads();
      stage64s(&Ks[0][0], kbase + (size_t)j0 * 2048, 2048, w, l);
#pragma unroll
      for (int j = 0; j < 2; ++j) {          // V tile [d][j]
        const int chunk = (w * 2 + j) * 64 + l;
        const int row = chunk >> 3, slot = chunk & 7;
        GLDS16(vbase + (size_t)row * Tn + j0 + ((slot ^ (row & 7)) << 3),
               &Vs[0][0] + (size_t)(w * 2 + j) * 512);
      }
      if (tid < 64) {
        m2s[tid] = m2buf[(size_t)bh * Tn + j0 + tid];
        rls[tid] = rlbuf[(size_t)bh * Tn + j0 + tid];
      }
      __syncthreads();
      // S = Q K^T (this wave's 16 rows x 64 cols)
      f32x4 s[4];
#pragma unroll
      for (int ni = 0; ni < 4; ++ni) s[ni] = (f32x4){0.f, 0.f, 0.f, 0.f};
#pragma unroll
      for (int kk = 0; kk < 2; ++kk) {
        const int ar = w * 16 + (l & 15);
        const short8 af = *(const short8*)&Qs[ar][(((l >> 4) + kk * 4) ^ (ar & 7)) << 3];
#pragma unroll
        for (int ni = 0; ni < 4; ++ni) {
          const int br = ni * 16 + (l & 15);
          const short8 bfr = *(const short8*)&Ks[br][(((l >> 4) + kk * 4) ^ (br & 7)) << 3];
          s[ni] = __builtin_amdgcn_mfma_f32_16x16x32_bf16(af, bfr, s[ni], 0, 0, 0);
        }
      }
      // P = exp2(s2 - m2_j) * rl_j  (masked), wave-private Ps rows
      const bool diag = (j0 == i0);
      const int ib = w * 16 + ((l >> 4) << 2);
      unsigned short* Pf = &Ps[0][0];
#pragma unroll
      for (int ni = 0; ni < 4; ++ni) {
        const int jl = ni * 16 + (l & 15);
        const float mj = m2s[jl], rj = rls[jl];
#pragma unroll
        for (int r = 0; r < 4; ++r) {
          float p = exp2f(s[ni][r] * S2 - mj) * rj;
          if (diag && (ib + r < jl)) p = 0.f;
          const int il = ib + r;
          Pf[il * 64 + (((jl >> 3) ^ (il & 7)) << 3) + (jl & 7)] = f2bf(p);
        }
      }
      // O += P V
#pragma unroll
      for (int kk = 0; kk < 2; ++kk) {
        const int ar = w * 16 + (l & 15);
        const short8 pf = *(const short8*)&Ps[ar][(((l >> 4) + kk * 4) ^ (ar & 7)) << 3];
#pragma unroll
        for (int ni = 0; ni < 4; ++ni) {
          const int br = ni * 16 + (l & 15);
          const short8 vf = *(const short8*)&Vs[br][(((l >> 4) + kk * 4) ^ (br & 7)) << 3];
          oacc[ni] = __builtin_amdgcn_mfma_f32_16x16x32_bf16(pf, vf, oacc[ni], 0, 0, 0);
        }
      }
    }
#pragma unroll
    for (int ni = 0; ni < 4; ++ni) {
      const int col = h * 64 + ni * 16 + (l & 15);
#pragma unroll
      for (int r = 0; r < 4; ++r) {
        const int m = b * Tn + i0 + w * 16 + ((l >> 4) << 2) + r;
        att[(size_t)m * 1024 + col] = f2bf(oacc[ni][r]);
      }
    }
  }
}

// ---------------------------------------------------------------------------
extern "C" void kernel_launch(void* const* d_in, const int* in_sizes, int n_in,
                              void* d_out, int out_size, void* d_ws, size_t ws_size,
                              hipStream_t stream) {
  const float* x    = (const float*)d_in[0];
  const float* ln1w = (const float*)d_in[1];
  const float* Wq   = (const float*)d_in[2];
  const float* bq   = (const float*)d_in[3];
  const float* Wk   = (const float*)d_in[4];
  const float* bk   = (const float*)d_in[5];
  const float* Wv   = (const float*)d_in[6];
  const float* bv   = (const float*)d_in[7];
  const float* Wo   = (const float*)d_in[8];
  const float* bo   = (const float*)d_in[9];
  const float* ln2w = (const float*)d_in[10];
  const float* W1   = (const float*)d_in[11];
  const float* b1   = (const float*)d_in[12];
  const float* W2   = (const float*)d_in[13];
  const float* b2   = (const float*)d_in[14];

  uint8_t* wsb = (uint8_t*)d_ws;
  unsigned short* h     = (unsigned short*)(wsb);                    // 8 MB
  unsigned short* qkb   = (unsigned short*)(wsb + (8ull  << 20));    // 16 MB (q|k)
  unsigned short* vT    = (unsigned short*)(wsb + (24ull << 20));    // 8 MB (=qkb+Mn*2048)
  unsigned short* attb  = (unsigned short*)(wsb + (32ull << 20));    // 8 MB
  float*          x1    = (float*)         (wsb + (40ull << 20));    // 16 MB
  unsigned short* ffmid = qkb;   // reuses qkb+vT+attb (32 MB), dead by then
  unsigned short* Wqkvt = (unsigned short*)(wsb + (56ull << 20));    // 6 MB [3072][1024]
  unsigned short* Wot   = (unsigned short*)(wsb + (62ull << 20));    // 2 MB
  unsigned short* W1t   = (unsigned short*)(wsb + (64ull << 20));    // 8 MB
  unsigned short* W2t   = (unsigned short*)(wsb + (72ull << 20));    // 8 MB
  float*          biasqkv=(float*)         (wsb + (80ull << 20));    // 12 KB
  float*          m2buf = (float*)         (wsb + (81ull << 20));    // 256 KB
  float*          rlbuf = (float*)         (wsb + (81ull << 20) + (256ull << 10));

  // weights -> bf16 B^T.  Wqkvt rows: [0,2048)=Wq|Wk, [2048,3072)=Wv.
  transpose_cvt<<<dim3(2, 32, 16), 256, 0, stream>>>(Wq, Wqkvt,                  1024, 64, 65536, 65536);
  transpose_cvt<<<dim3(2, 32, 16), 256, 0, stream>>>(Wk, Wqkvt + 1024 * 1024,    1024, 64, 65536, 65536);
  transpose_cvt<<<dim3(2, 32, 16), 256, 0, stream>>>(Wv, Wqkvt + 2 * 1024 * 1024, 1024, 64, 65536, 65536);
  transpose_cvt<<<dim3(32, 32, 1), 256, 0, stream>>>(Wo, Wot,  1024, 1024, 0, 0);
  transpose_cvt<<<dim3(128, 32, 1), 256, 0, stream>>>(W1, W1t, 1024, 4096, 0, 0);
  transpose_cvt<<<dim3(32, 128, 1), 256, 0, stream>>>(W2, W2t, 4096, 1024, 0, 0);
  hipMemcpyAsync(biasqkv,        bq, 1024 * sizeof(float), hipMemcpyDeviceToDevice, stream);
  hipMemcpyAsync(biasqkv + 1024, bk, 1024 * sizeof(float), hipMemcpyDeviceToDevice, stream);
  hipMemcpyAsync(biasqkv + 2048, bv, 1024 * sizeof(float), hipMemcpyDeviceToDevice, stream);

  // 1. LN1 -> h (bf16)
  ln_bf16<<<Mn, 256, 0, stream>>>(x, ln1w, h);
  // 2. fused q|k|v = h @ Wqkv  (N=3072; single-buffer, 3 blk/CU)
  gemm_bf16<0, 3, 0><<<dim3(24, 32), 256, 0, stream>>>(h, Wqkvt, biasqkv, nullptr, qkb, Mn, 3072, Cn);
  // 3/4. column-softmax attention (triangle-paired)
  colstats_mfma<<<dim3(16, Bn * Hn), 256, 0, stream>>>(qkb, m2buf, rlbuf);
  pv_mfma<<<dim3(16, Bn * Hn), 256, 0, stream>>>(qkb, vT, m2buf, rlbuf, attb);
  // 5. x1 = att @ Wo + bo + x  (fp32 out; dbuf for ILP at 1 blk/CU)
  gemm_bf16<2, 0, 1><<<dim3(8, 32), 256, 0, stream>>>(attb, Wot, bo, x, x1, Mn, 1024, Cn);
  // 6. LN2 -> h (bf16)
  ln_bf16<<<Mn, 256, 0, stream>>>(x1, ln2w, h);
  // 7. ffmid = relu(h @ W1 + b1)  (single-buffer, 4 blk/CU)
  gemm_bf16<1, 1, 0><<<dim3(32, 32), 256, 0, stream>>>(h, W1t, b1, nullptr, ffmid, Mn, FFn, Cn);
  // 8. out = b2 + x1, then split-K=2 FFN2 atomically accumulates
  init_out<<<Mn * Cn / 1024, 256, 0, stream>>>(b2, x1, (float*)d_out);
  gemm_bf16<3, 0, 1><<<dim3(8, 32, 2), 256, 0, stream>>>(ffmid, W2t, nullptr, nullptr, (float*)d_out, Mn, Cn, FFn);
}